// Round 8
// baseline (140.694 us; speedup 1.0000x reference)
//
#include <hip/hip_runtime.h>

// GCN 2-layer forward on MI355X — atomic-free clustered CSR build + 8-lane gather
// + MFMA bf16 feature transform with LDS-staged vectorized epilogue.
// N=150000, E=1.2M, IN=HID=64, layer-2 out dim = 1.
//
// pre1 = dinv[v]*(sum_{e:dst=v} Y[src] + Y[v]) + b1,  Y = (x@W1) row-scaled by dinv (bf16)
// zs   = (relu(pre1).W2) * dinv
// out  = relu(dinv[v]*(sum zs[src] + zs[v]) + b2), sliced v%15 in 3..14

#define BK 256        // nodes per bucket
#define NBMAX 640     // >= NB=586
#define EPB 8192      // edges per block for hist/place
#define HB 160        // padded per-bucket row length (>= nblk=147)

typedef unsigned int uint;
typedef unsigned short ushort;
typedef __attribute__((ext_vector_type(8))) short bf16x8_t;
typedef __attribute__((ext_vector_type(4))) float f32x4_t;

static __device__ __forceinline__ ushort f2bf(float x) {
    uint u = __float_as_uint(x);
    u = (u + 0x7FFFu + ((u >> 16) & 1u)) >> 16;   // RN-even
    return (ushort)u;
}

// per-block LDS histogram of dst>>8 -> hist[j*HB + b]; block 0 zeroes the ticket
__global__ __launch_bounds__(256) void k_hist(const int* __restrict__ dst, int E, int nb,
                                              int* __restrict__ hist, int* __restrict__ ticket) {
    __shared__ int h[NBMAX];
    const int t = threadIdx.x, b = blockIdx.x;
    if (b == 0 && t == 0) ticket[0] = 0;
    for (int j = t; j < nb; j += 256) h[j] = 0;
    __syncthreads();
    const int e0 = b * EPB, e1 = min(e0 + EPB, E);
    for (int e = e0 + t; e < e1; e += 256) atomicAdd(&h[dst[e] >> 8], 1);
    __syncthreads();
    for (int j = t; j < nb; j += 256) hist[j * HB + b] = h[j];
}

// Fused column scan: per bucket j, exclusive prefix over blocks (in place) and
// column total; the LAST block (device ticket) then scans the 586 column totals
// into boff[nb+1] and writes rowptr[N]=E.
__global__ __launch_bounds__(256) void k_cscan(int* __restrict__ hist, int nblk, int nb, int N,
                                               int* __restrict__ colsum, int* __restrict__ boff,
                                               int* __restrict__ rowptr, int* __restrict__ ticket) {
    __shared__ int s[256];
    __shared__ int lastflag;
    const int j = blockIdx.x, t = threadIdx.x;
    int v = (t < nblk) ? hist[j * HB + t] : 0;
    s[t] = v;
    __syncthreads();
    for (int o = 1; o < 256; o <<= 1) {
        int x = s[t];
        if (t >= o) x += s[t - o];
        __syncthreads();
        s[t] = x;
        __syncthreads();
    }
    if (t < nblk) hist[j * HB + t] = s[t] - v;
    if (t == 255) colsum[j] = s[t];
    __threadfence();
    if (t == 0) lastflag = (atomicAdd(ticket, 1) == gridDim.x - 1) ? 1 : 0;
    __syncthreads();
    if (!lastflag) return;

    // last block: exclusive scan of colsum[nb] (nb may exceed 256 -> chunked with carry)
    int carry = 0;
    for (int base = 0; base < nb; base += 256) {
        int idx = base + t;
        int val = (idx < nb) ? colsum[idx] : 0;
        __syncthreads();
        s[t] = val;
        __syncthreads();
        for (int o = 1; o < 256; o <<= 1) {
            int x = s[t];
            if (t >= o) x += s[t - o];
            __syncthreads();
            s[t] = x;
            __syncthreads();
        }
        if (idx < nb) boff[idx] = carry + s[t] - val;
        carry += s[255];
    }
    if (t == 0) { boff[nb] = carry; rowptr[N] = carry; }
}

// place edges into per-(block,bucket) reserved chunks (clustered writes, LDS cursors)
__global__ __launch_bounds__(256) void k_place(const int* __restrict__ src, const int* __restrict__ dst,
                                               int E, int nb, const int* __restrict__ hist,
                                               const int* __restrict__ boff, uint* __restrict__ ebuf) {
    __shared__ int cur[NBMAX];
    const int t = threadIdx.x, b = blockIdx.x;
    for (int j = t; j < nb; j += 256) cur[j] = boff[j] + hist[j * HB + b];
    __syncthreads();
    const int e0 = b * EPB, e1 = min(e0 + EPB, E);
    for (int e = e0 + t; e < e1; e += 256) {
        int d = dst[e];
        int p = atomicAdd(&cur[d >> 8], 1);
        ebuf[p] = ((uint)(d & 255) << 24) | (uint)src[e];
    }
}

// per bucket: node histogram (=deg) -> dinv + rowptr (local scan) + csrc placement
__global__ __launch_bounds__(256) void k_fill3(const uint* __restrict__ ebuf, const int* __restrict__ boff,
                                               int N, int* __restrict__ rowptr, float* __restrict__ dinv,
                                               int* __restrict__ csrc) {
    __shared__ int cnt[BK];
    __shared__ int sc[BK];
    __shared__ int cur[BK];
    const int b = blockIdx.x, v0 = b << 8, t = threadIdx.x;
    const int nv = min(BK, N - v0);
    cnt[t] = 0;
    __syncthreads();
    const int bb = boff[b], be = boff[b + 1];
    for (int j = bb + t; j < be; j += 256) atomicAdd(&cnt[ebuf[j] >> 24], 1);
    __syncthreads();
    const int c = cnt[t];
    if (t < nv) dinv[v0 + t] = rsqrtf((float)c + 1.0f);
    sc[t] = c;
    __syncthreads();
    for (int o = 1; o < 256; o <<= 1) {
        int x = sc[t];
        if (t >= o) x += sc[t - o];
        __syncthreads();
        sc[t] = x;
        __syncthreads();
    }
    const int ex = sc[t] - c + bb;
    if (t < nv) rowptr[v0 + t] = ex;
    cur[t] = ex;
    __syncthreads();
    for (int j = bb + t; j < be; j += 256) {
        uint e = ebuf[j];
        int p = atomicAdd(&cur[e >> 24], 1);
        csrc[p] = (int)(e & 0xFFFFFFu);
    }
}

// MFMA feature transform: Y = (X @ W1) * dinv, emitted bf16.
// Block = 256 threads = 4 waves; wave handles 16 rows; 8x mfma_f32_16x16x32_bf16.
// C-tile staged in LDS, then written out as uint4 (8 bf16) fully coalesced.
__global__ __launch_bounds__(256) void k_gemm1(const float* __restrict__ X, const float* __restrict__ W,
                                               const float* __restrict__ dinv, int N,
                                               ushort* __restrict__ Yh) {
    __shared__ __align__(16) ushort Wt[64 * 72];  // Wt[col][k]
    __shared__ __align__(16) ushort Ot[64 * 72];  // C tile (bf16, scaled)
    const int t = threadIdx.x;

    // stage W^T as bf16 (one-time, 4096 elems)
#pragma unroll
    for (int i = 0; i < 4; i++) {
        int idx = t + i * 256;          // float4 index, 0..1023
        int k = idx >> 4;
        int c4 = idx & 15;
        float4 w4 = ((const float4*)W)[idx];
        Wt[(c4 * 4 + 0) * 72 + k] = f2bf(w4.x);
        Wt[(c4 * 4 + 1) * 72 + k] = f2bf(w4.y);
        Wt[(c4 * 4 + 2) * 72 + k] = f2bf(w4.z);
        Wt[(c4 * 4 + 3) * 72 + k] = f2bf(w4.w);
    }
    __syncthreads();

    const int l = t & 63;
    const int lr = l & 15;                       // A-row / B-col within tile
    const int g = l >> 4;                        // k-group
    const int wv = t >> 6;                       // wave id
    const int row0 = blockIdx.x * 64;
    const int rw = row0 + wv * 16;               // wave's row base

    // A fragments for the two K=32 steps (row = rw+lr, k = s*32 + g*8 + i)
    bf16x8_t afr[2];
#pragma unroll
    for (int s = 0; s < 2; s++) {
        const int row = rw + lr;
        float4 xa = make_float4(0.f, 0.f, 0.f, 0.f), xb = xa;
        if (row < N) {
            const float4* xp = (const float4*)(X + (size_t)row * 64 + s * 32 + g * 8);
            xa = xp[0];
            xb = xp[1];
        }
        bf16x8_t af;
        af[0] = (short)f2bf(xa.x); af[1] = (short)f2bf(xa.y);
        af[2] = (short)f2bf(xa.z); af[3] = (short)f2bf(xa.w);
        af[4] = (short)f2bf(xb.x); af[5] = (short)f2bf(xb.y);
        af[6] = (short)f2bf(xb.z); af[7] = (short)f2bf(xb.w);
        afr[s] = af;
    }

    // dinv for this lane's 4 C-rows (reads past N stay inside the workspace)
    const float4 dv = *(const float4*)(dinv + rw + g * 4);

#pragma unroll
    for (int c = 0; c < 4; c++) {
        f32x4_t acc = {0.f, 0.f, 0.f, 0.f};
#pragma unroll
        for (int s = 0; s < 2; s++) {
            const bf16x8_t bf = *(const bf16x8_t*)&Wt[(c * 16 + lr) * 72 + s * 32 + g * 8];
            acc = __builtin_amdgcn_mfma_f32_16x16x32_bf16(afr[s], bf, acc, 0, 0, 0);
        }
        const int col = c * 16 + lr;
#pragma unroll
        for (int r = 0; r < 4; r++) {
            const float sc = (r == 0) ? dv.x : (r == 1) ? dv.y : (r == 2) ? dv.z : dv.w;
            Ot[(wv * 16 + g * 4 + r) * 72 + col] = f2bf(acc[r] * sc);
        }
    }
    __syncthreads();

    // vectorized writeout: 2 x uint4 (8 bf16) per thread, fully coalesced
#pragma unroll
    for (int i = 0; i < 2; i++) {
        int vi = t + i * 256;            // 0..511
        int row = vi >> 3;
        int c8 = vi & 7;
        int grow = row0 + row;
        if (grow < N)
            ((uint4*)(Yh + (size_t)grow * 64))[c8] = *(const uint4*)&Ot[row * 72 + c8 * 8];
    }
}

// Fused layer-1 gather + bias/relu + dot(W2) + *dinv -> zs.
// 8 lanes per node; lane li owns features 8li..8li+7 (uint4 = 8 bf16).
__global__ __launch_bounds__(256) void k_agg(const ushort* __restrict__ Yh, const int* __restrict__ rowptr,
                                             const int* __restrict__ csrc, const float* __restrict__ dinv,
                                             const float* __restrict__ b1, const float* __restrict__ W2,
                                             int N, float* __restrict__ zs) {
    int t = blockIdx.x * 256 + threadIdx.x;
    int v = t >> 3;
    if (v >= N) return;
    int li = t & 7;
    const uint4* Y4 = (const uint4*)Yh;
    int start = rowptr[v];
    int cnt = rowptr[v + 1] - start;

    float a[8];
    {
        uint4 m = Y4[(size_t)v * 8 + li];  // self-loop term
        a[0] = __uint_as_float(m.x << 16);
        a[1] = __uint_as_float(m.x & 0xFFFF0000u);
        a[2] = __uint_as_float(m.y << 16);
        a[3] = __uint_as_float(m.y & 0xFFFF0000u);
        a[4] = __uint_as_float(m.z << 16);
        a[5] = __uint_as_float(m.z & 0xFFFF0000u);
        a[6] = __uint_as_float(m.w << 16);
        a[7] = __uint_as_float(m.w & 0xFFFF0000u);
    }

    for (int j0 = 0; j0 < cnt; j0 += 8) {
        int rem = cnt - j0;
        int myidx = 0;
        if (li < rem) myidx = csrc[start + j0 + li];  // one coalesced 32B read per 8 edges
#pragma unroll
        for (int k = 0; k < 8; k++) {
            if (k < rem) {
                int s = __shfl(myidx, k, 8);
                uint4 m = Y4[(size_t)s * 8 + li];     // independent 16B loads -> ILP
                a[0] += __uint_as_float(m.x << 16);
                a[1] += __uint_as_float(m.x & 0xFFFF0000u);
                a[2] += __uint_as_float(m.y << 16);
                a[3] += __uint_as_float(m.y & 0xFFFF0000u);
                a[4] += __uint_as_float(m.z << 16);
                a[5] += __uint_as_float(m.z & 0xFFFF0000u);
                a[6] += __uint_as_float(m.w << 16);
                a[7] += __uint_as_float(m.w & 0xFFFF0000u);
            }
        }
    }

    float dv = dinv[v];
    float4 ba = ((const float4*)b1)[2 * li], bb = ((const float4*)b1)[2 * li + 1];
    float4 wa = ((const float4*)W2)[2 * li], wb = ((const float4*)W2)[2 * li + 1];
    float p;
    p  = fmaxf(fmaf(dv, a[0], ba.x), 0.f) * wa.x;
    p += fmaxf(fmaf(dv, a[1], ba.y), 0.f) * wa.y;
    p += fmaxf(fmaf(dv, a[2], ba.z), 0.f) * wa.z;
    p += fmaxf(fmaf(dv, a[3], ba.w), 0.f) * wa.w;
    p += fmaxf(fmaf(dv, a[4], bb.x), 0.f) * wb.x;
    p += fmaxf(fmaf(dv, a[5], bb.y), 0.f) * wb.y;
    p += fmaxf(fmaf(dv, a[6], bb.z), 0.f) * wb.z;
    p += fmaxf(fmaf(dv, a[7], bb.w), 0.f) * wb.w;
    p += __shfl_xor(p, 1);
    p += __shfl_xor(p, 2);
    p += __shfl_xor(p, 4);
    if (li == 0) zs[v] = p * dv;
}

// layer-2 scalar gather + output slice: v = (i/12)*15 + 3 + i%12
__global__ __launch_bounds__(256) void k_out2(const float* __restrict__ zs, const int* __restrict__ rowptr,
                                              const int* __restrict__ csrc, const float* __restrict__ dinv,
                                              const float* __restrict__ b2, int M, float* __restrict__ out) {
    int i = blockIdx.x * 256 + threadIdx.x;
    if (i >= M) return;
    int q = i / 12;
    int c = i - q * 12;
    int v = q * 15 + 3 + c;
    int j = rowptr[v];
    const int end = rowptr[v + 1];
    float s = zs[v];
    for (; j + 4 <= end; j += 4) {
        int i0 = csrc[j], i1 = csrc[j + 1], i2 = csrc[j + 2], i3 = csrc[j + 3];
        s += zs[i0] + zs[i1] + zs[i2] + zs[i3];   // 4 independent L2-hot loads
    }
    for (; j < end; j++) s += zs[csrc[j]];
    out[i] = fmaxf(fmaf(dinv[v], s, b2[0]), 0.f);
}

extern "C" void kernel_launch(void* const* d_in, const int* in_sizes, int n_in,
                              void* d_out, int out_size, void* d_ws, size_t ws_size,
                              hipStream_t stream) {
    const float* obs = (const float*)d_in[0];
    const int*   ei  = (const int*)d_in[1];   // [2,E]; JAX x64-off -> int32
    const float* W1  = (const float*)d_in[2];
    const float* b1  = (const float*)d_in[3];
    const float* W2  = (const float*)d_in[4];
    const float* b2  = (const float*)d_in[5];

    const int N = in_sizes[0] / 64;
    const int E = in_sizes[1] / 2;
    const int M = out_size;
    const int NB = (N + BK - 1) / BK;          // 586
    const int NBLK = (E + EPB - 1) / EPB;      // 147 (<= HB, <= 256)

    const int* src = ei;
    const int* dst = ei + E;

    // workspace layout
    ushort* Yh     = (ushort*)d_ws;                  // N*64 bf16 (19.2 MB)
    float*  dinv   = (float*)(Yh + (size_t)N * 64);  // N
    float*  zs     = dinv + N;                       // N
    int*    rowptr = (int*)(zs + N);                 // N+1
    int*    colsum = rowptr + N + 1;                 // NBMAX
    int*    boff   = colsum + NBMAX;                 // NBMAX+1
    int*    ticket = boff + NBMAX + 1;               // 1
    int*    hist   = ticket + 1;                     // NBMAX*HB (410 KB)
    uint*   ebuf   = (uint*)(hist + NBMAX * HB);     // E (4.8 MB)
    int*    csrc   = (int*)(ebuf + E);               // E (4.8 MB)

    k_hist <<<NBLK, 256, 0, stream>>>(dst, E, NB, hist, ticket);
    k_cscan<<<NB, 256, 0, stream>>>(hist, NBLK, NB, N, colsum, boff, rowptr, ticket);
    k_place<<<NBLK, 256, 0, stream>>>(src, dst, E, NB, hist, boff, ebuf);
    k_fill3<<<NB, 256, 0, stream>>>(ebuf, boff, N, rowptr, dinv, csrc);
    k_gemm1<<<(N + 63) / 64, 256, 0, stream>>>(obs, W1, dinv, N, Yh);
    k_agg  <<<((size_t)N * 8 + 255) / 256, 256, 0, stream>>>(Yh, rowptr, csrc, dinv, b1, W2, N, zs);
    k_out2 <<<(M + 255) / 256, 256, 0, stream>>>(zs, rowptr, csrc, dinv, b2, M, (float*)d_out);
}

// Round 9
// 102.551 us; speedup vs baseline: 1.3719x; 1.3719x over previous
//
#include <hip/hip_runtime.h>

// GCN 2-layer forward on MI355X — atomic-free clustered CSR build + 8-lane gather
// + MFMA bf16 feature transform with LDS-staged vectorized epilogue.
// N=150000, E=1.2M, IN=HID=64, layer-2 out dim = 1.
//
// pre1 = dinv[v]*(sum_{e:dst=v} Y[src] + Y[v]) + b1,  Y = (x@W1) row-scaled by dinv (bf16)
// zs   = (relu(pre1).W2) * dinv
// out  = relu(dinv[v]*(sum zs[src] + zs[v]) + b2), sliced v%15 in 3..14
//
// NOTE (round 8 lesson): fusing the two scan kernels with a device-scope
// ticket + __threadfence cost 40 µs (fence chain serializes across XCDs).
// Kernel boundary is cheaper than device-scope fencing here.

#define BK 256        // nodes per bucket
#define NBMAX 640     // >= NB=586
#define EPB 8192      // edges per block for hist/place
#define HB 160        // padded per-bucket row length (>= nblk=147)

typedef unsigned int uint;
typedef unsigned short ushort;
typedef __attribute__((ext_vector_type(8))) short bf16x8_t;
typedef __attribute__((ext_vector_type(4))) float f32x4_t;

static __device__ __forceinline__ ushort f2bf(float x) {
    uint u = __float_as_uint(x);
    u = (u + 0x7FFFu + ((u >> 16) & 1u)) >> 16;   // RN-even
    return (ushort)u;
}

// per-block LDS histogram of dst>>8 -> hist[j*HB + b]
__global__ __launch_bounds__(256) void k_hist(const int* __restrict__ dst, int E, int nb,
                                              int* __restrict__ hist) {
    __shared__ int h[NBMAX];
    const int t = threadIdx.x, b = blockIdx.x;
    for (int j = t; j < nb; j += 256) h[j] = 0;
    __syncthreads();
    const int e0 = b * EPB, e1 = min(e0 + EPB, E);
    for (int e = e0 + t; e < e1; e += 256) atomicAdd(&h[dst[e] >> 8], 1);
    __syncthreads();
    for (int j = t; j < nb; j += 256) hist[j * HB + b] = h[j];
}

// per bucket j: exclusive prefix over blocks (in place), column total -> colsum[j]
__global__ __launch_bounds__(256) void k_cscan1(int* __restrict__ hist, int nblk,
                                                int* __restrict__ colsum) {
    __shared__ int s[256];
    const int j = blockIdx.x, t = threadIdx.x;
    int v = (t < nblk) ? hist[j * HB + t] : 0;
    s[t] = v;
    __syncthreads();
    for (int o = 1; o < 256; o <<= 1) {
        int x = s[t];
        if (t >= o) x += s[t - o];
        __syncthreads();
        s[t] = x;
        __syncthreads();
    }
    if (t < nblk) hist[j * HB + t] = s[t] - v;
    if (t == 255) colsum[j] = s[t];
}

// single block: exclusive scan colsum[nb] -> boff[nb+1]; rowptr[N] = E
__global__ __launch_bounds__(1024) void k_cscan2(const int* __restrict__ colsum, int nb, int N,
                                                 int* __restrict__ boff, int* __restrict__ rowptr) {
    __shared__ int s[1024];
    const int t = threadIdx.x;
    int v = (t < nb) ? colsum[t] : 0;
    s[t] = v;
    __syncthreads();
    for (int o = 1; o < 1024; o <<= 1) {
        int x = s[t];
        if (t >= o) x += s[t - o];
        __syncthreads();
        s[t] = x;
        __syncthreads();
    }
    if (t < nb) boff[t] = s[t] - v;
    if (t == nb - 1) { boff[nb] = s[t]; rowptr[N] = s[t]; }
}

// place edges into per-(block,bucket) reserved chunks (clustered writes, LDS cursors)
__global__ __launch_bounds__(256) void k_place(const int* __restrict__ src, const int* __restrict__ dst,
                                               int E, int nb, const int* __restrict__ hist,
                                               const int* __restrict__ boff, uint* __restrict__ ebuf) {
    __shared__ int cur[NBMAX];
    const int t = threadIdx.x, b = blockIdx.x;
    for (int j = t; j < nb; j += 256) cur[j] = boff[j] + hist[j * HB + b];
    __syncthreads();
    const int e0 = b * EPB, e1 = min(e0 + EPB, E);
    for (int e = e0 + t; e < e1; e += 256) {
        int d = dst[e];
        int p = atomicAdd(&cur[d >> 8], 1);
        ebuf[p] = ((uint)(d & 255) << 24) | (uint)src[e];
    }
}

// per bucket: node histogram (=deg) -> dinv + rowptr (local scan) + csrc placement
__global__ __launch_bounds__(256) void k_fill3(const uint* __restrict__ ebuf, const int* __restrict__ boff,
                                               int N, int* __restrict__ rowptr, float* __restrict__ dinv,
                                               int* __restrict__ csrc) {
    __shared__ int cnt[BK];
    __shared__ int sc[BK];
    __shared__ int cur[BK];
    const int b = blockIdx.x, v0 = b << 8, t = threadIdx.x;
    const int nv = min(BK, N - v0);
    cnt[t] = 0;
    __syncthreads();
    const int bb = boff[b], be = boff[b + 1];
    for (int j = bb + t; j < be; j += 256) atomicAdd(&cnt[ebuf[j] >> 24], 1);
    __syncthreads();
    const int c = cnt[t];
    if (t < nv) dinv[v0 + t] = rsqrtf((float)c + 1.0f);
    sc[t] = c;
    __syncthreads();
    for (int o = 1; o < 256; o <<= 1) {
        int x = sc[t];
        if (t >= o) x += sc[t - o];
        __syncthreads();
        sc[t] = x;
        __syncthreads();
    }
    const int ex = sc[t] - c + bb;
    if (t < nv) rowptr[v0 + t] = ex;
    cur[t] = ex;
    __syncthreads();
    for (int j = bb + t; j < be; j += 256) {
        uint e = ebuf[j];
        int p = atomicAdd(&cur[e >> 24], 1);
        csrc[p] = (int)(e & 0xFFFFFFu);
    }
}

// MFMA feature transform: Y = (X @ W1) * dinv, emitted bf16.
// Block = 256 threads = 4 waves; wave handles 16 rows; 8x mfma_f32_16x16x32_bf16.
// C-tile staged in LDS, then written out as uint4 (8 bf16) fully coalesced.
__global__ __launch_bounds__(256) void k_gemm1(const float* __restrict__ X, const float* __restrict__ W,
                                               const float* __restrict__ dinv, int N,
                                               ushort* __restrict__ Yh) {
    __shared__ __align__(16) ushort Wt[64 * 72];  // Wt[col][k]
    __shared__ __align__(16) ushort Ot[64 * 72];  // C tile (bf16, scaled)
    const int t = threadIdx.x;

    // stage W^T as bf16 (one-time, 4096 elems)
#pragma unroll
    for (int i = 0; i < 4; i++) {
        int idx = t + i * 256;          // float4 index, 0..1023
        int k = idx >> 4;
        int c4 = idx & 15;
        float4 w4 = ((const float4*)W)[idx];
        Wt[(c4 * 4 + 0) * 72 + k] = f2bf(w4.x);
        Wt[(c4 * 4 + 1) * 72 + k] = f2bf(w4.y);
        Wt[(c4 * 4 + 2) * 72 + k] = f2bf(w4.z);
        Wt[(c4 * 4 + 3) * 72 + k] = f2bf(w4.w);
    }
    __syncthreads();

    const int l = t & 63;
    const int lr = l & 15;                       // A-row / B-col within tile
    const int g = l >> 4;                        // k-group
    const int wv = t >> 6;                       // wave id
    const int row0 = blockIdx.x * 64;
    const int rw = row0 + wv * 16;               // wave's row base

    // A fragments for the two K=32 steps (row = rw+lr, k = s*32 + g*8 + i)
    bf16x8_t afr[2];
#pragma unroll
    for (int s = 0; s < 2; s++) {
        const int row = rw + lr;
        float4 xa = make_float4(0.f, 0.f, 0.f, 0.f), xb = xa;
        if (row < N) {
            const float4* xp = (const float4*)(X + (size_t)row * 64 + s * 32 + g * 8);
            xa = xp[0];
            xb = xp[1];
        }
        bf16x8_t af;
        af[0] = (short)f2bf(xa.x); af[1] = (short)f2bf(xa.y);
        af[2] = (short)f2bf(xa.z); af[3] = (short)f2bf(xa.w);
        af[4] = (short)f2bf(xb.x); af[5] = (short)f2bf(xb.y);
        af[6] = (short)f2bf(xb.z); af[7] = (short)f2bf(xb.w);
        afr[s] = af;
    }

    // dinv for this lane's 4 C-rows (reads past N stay inside the workspace)
    const float4 dv = *(const float4*)(dinv + rw + g * 4);

#pragma unroll
    for (int c = 0; c < 4; c++) {
        f32x4_t acc = {0.f, 0.f, 0.f, 0.f};
#pragma unroll
        for (int s = 0; s < 2; s++) {
            const bf16x8_t bf = *(const bf16x8_t*)&Wt[(c * 16 + lr) * 72 + s * 32 + g * 8];
            acc = __builtin_amdgcn_mfma_f32_16x16x32_bf16(afr[s], bf, acc, 0, 0, 0);
        }
        const int col = c * 16 + lr;
#pragma unroll
        for (int r = 0; r < 4; r++) {
            const float sc = (r == 0) ? dv.x : (r == 1) ? dv.y : (r == 2) ? dv.z : dv.w;
            Ot[(wv * 16 + g * 4 + r) * 72 + col] = f2bf(acc[r] * sc);
        }
    }
    __syncthreads();

    // vectorized writeout: 2 x uint4 (8 bf16) per thread, fully coalesced
#pragma unroll
    for (int i = 0; i < 2; i++) {
        int vi = t + i * 256;            // 0..511
        int row = vi >> 3;
        int c8 = vi & 7;
        int grow = row0 + row;
        if (grow < N)
            ((uint4*)(Yh + (size_t)grow * 64))[c8] = *(const uint4*)&Ot[row * 72 + c8 * 8];
    }
}

// Fused layer-1 gather + bias/relu + dot(W2) + *dinv -> zs.
// 8 lanes per node; lane li owns features 8li..8li+7 (uint4 = 8 bf16).
__global__ __launch_bounds__(256) void k_agg(const ushort* __restrict__ Yh, const int* __restrict__ rowptr,
                                             const int* __restrict__ csrc, const float* __restrict__ dinv,
                                             const float* __restrict__ b1, const float* __restrict__ W2,
                                             int N, float* __restrict__ zs) {
    int t = blockIdx.x * 256 + threadIdx.x;
    int v = t >> 3;
    if (v >= N) return;
    int li = t & 7;
    const uint4* Y4 = (const uint4*)Yh;
    int start = rowptr[v];
    int cnt = rowptr[v + 1] - start;

    float a[8];
    {
        uint4 m = Y4[(size_t)v * 8 + li];  // self-loop term
        a[0] = __uint_as_float(m.x << 16);
        a[1] = __uint_as_float(m.x & 0xFFFF0000u);
        a[2] = __uint_as_float(m.y << 16);
        a[3] = __uint_as_float(m.y & 0xFFFF0000u);
        a[4] = __uint_as_float(m.z << 16);
        a[5] = __uint_as_float(m.z & 0xFFFF0000u);
        a[6] = __uint_as_float(m.w << 16);
        a[7] = __uint_as_float(m.w & 0xFFFF0000u);
    }

    for (int j0 = 0; j0 < cnt; j0 += 8) {
        int rem = cnt - j0;
        int myidx = 0;
        if (li < rem) myidx = csrc[start + j0 + li];  // one coalesced 32B read per 8 edges
#pragma unroll
        for (int k = 0; k < 8; k++) {
            if (k < rem) {
                int s = __shfl(myidx, k, 8);
                uint4 m = Y4[(size_t)s * 8 + li];     // independent 16B loads -> ILP
                a[0] += __uint_as_float(m.x << 16);
                a[1] += __uint_as_float(m.x & 0xFFFF0000u);
                a[2] += __uint_as_float(m.y << 16);
                a[3] += __uint_as_float(m.y & 0xFFFF0000u);
                a[4] += __uint_as_float(m.z << 16);
                a[5] += __uint_as_float(m.z & 0xFFFF0000u);
                a[6] += __uint_as_float(m.w << 16);
                a[7] += __uint_as_float(m.w & 0xFFFF0000u);
            }
        }
    }

    float dv = dinv[v];
    float4 ba = ((const float4*)b1)[2 * li], bb = ((const float4*)b1)[2 * li + 1];
    float4 wa = ((const float4*)W2)[2 * li], wb = ((const float4*)W2)[2 * li + 1];
    float p;
    p  = fmaxf(fmaf(dv, a[0], ba.x), 0.f) * wa.x;
    p += fmaxf(fmaf(dv, a[1], ba.y), 0.f) * wa.y;
    p += fmaxf(fmaf(dv, a[2], ba.z), 0.f) * wa.z;
    p += fmaxf(fmaf(dv, a[3], ba.w), 0.f) * wa.w;
    p += fmaxf(fmaf(dv, a[4], bb.x), 0.f) * wb.x;
    p += fmaxf(fmaf(dv, a[5], bb.y), 0.f) * wb.y;
    p += fmaxf(fmaf(dv, a[6], bb.z), 0.f) * wb.z;
    p += fmaxf(fmaf(dv, a[7], bb.w), 0.f) * wb.w;
    p += __shfl_xor(p, 1);
    p += __shfl_xor(p, 2);
    p += __shfl_xor(p, 4);
    if (li == 0) zs[v] = p * dv;
}

// layer-2 scalar gather + output slice: v = (i/12)*15 + 3 + i%12
__global__ __launch_bounds__(256) void k_out2(const float* __restrict__ zs, const int* __restrict__ rowptr,
                                              const int* __restrict__ csrc, const float* __restrict__ dinv,
                                              const float* __restrict__ b2, int M, float* __restrict__ out) {
    int i = blockIdx.x * 256 + threadIdx.x;
    if (i >= M) return;
    int q = i / 12;
    int c = i - q * 12;
    int v = q * 15 + 3 + c;
    int j = rowptr[v];
    const int end = rowptr[v + 1];
    float s = zs[v];
    for (; j + 4 <= end; j += 4) {
        int i0 = csrc[j], i1 = csrc[j + 1], i2 = csrc[j + 2], i3 = csrc[j + 3];
        s += zs[i0] + zs[i1] + zs[i2] + zs[i3];   // 4 independent L2-hot loads
    }
    for (; j < end; j++) s += zs[csrc[j]];
    out[i] = fmaxf(fmaf(dinv[v], s, b2[0]), 0.f);
}

extern "C" void kernel_launch(void* const* d_in, const int* in_sizes, int n_in,
                              void* d_out, int out_size, void* d_ws, size_t ws_size,
                              hipStream_t stream) {
    const float* obs = (const float*)d_in[0];
    const int*   ei  = (const int*)d_in[1];   // [2,E]; JAX x64-off -> int32
    const float* W1  = (const float*)d_in[2];
    const float* b1  = (const float*)d_in[3];
    const float* W2  = (const float*)d_in[4];
    const float* b2  = (const float*)d_in[5];

    const int N = in_sizes[0] / 64;
    const int E = in_sizes[1] / 2;
    const int M = out_size;
    const int NB = (N + BK - 1) / BK;          // 586
    const int NBLK = (E + EPB - 1) / EPB;      // 147 (<= HB, <= 256)

    const int* src = ei;
    const int* dst = ei + E;

    // workspace layout
    ushort* Yh     = (ushort*)d_ws;                  // N*64 bf16 (19.2 MB)
    float*  dinv   = (float*)(Yh + (size_t)N * 64);  // N
    float*  zs     = dinv + N;                       // N
    int*    rowptr = (int*)(zs + N);                 // N+1
    int*    colsum = rowptr + N + 1;                 // NBMAX
    int*    boff   = colsum + NBMAX;                 // NBMAX+1
    int*    hist   = boff + NBMAX + 1;               // NBMAX*HB (410 KB)
    uint*   ebuf   = (uint*)(hist + NBMAX * HB);     // E (4.8 MB)
    int*    csrc   = (int*)(ebuf + E);               // E (4.8 MB)

    k_hist  <<<NBLK, 256, 0, stream>>>(dst, E, NB, hist);
    k_cscan1<<<NB, 256, 0, stream>>>(hist, NBLK, colsum);
    k_cscan2<<<1, 1024, 0, stream>>>(colsum, NB, N, boff, rowptr);
    k_place <<<NBLK, 256, 0, stream>>>(src, dst, E, NB, hist, boff, ebuf);
    k_fill3 <<<NB, 256, 0, stream>>>(ebuf, boff, N, rowptr, dinv, csrc);
    k_gemm1 <<<(N + 63) / 64, 256, 0, stream>>>(obs, W1, dinv, N, Yh);
    k_agg   <<<((size_t)N * 8 + 255) / 256, 256, 0, stream>>>(Yh, rowptr, csrc, dinv, b1, W2, N, zs);
    k_out2  <<<(M + 255) / 256, 256, 0, stream>>>(zs, rowptr, csrc, dinv, b2, M, (float*)d_out);
}

// Round 10
// 95.594 us; speedup vs baseline: 1.4718x; 1.0728x over previous
//
#include <hip/hip_runtime.h>

// GCN 2-layer forward on MI355X — atomic-free clustered CSR build + pipelined
// 8-lane gather + MFMA bf16 feature transform (128-row blocks, LDS epilogue).
// N=150000, E=1.2M, IN=HID=64, layer-2 out dim = 1.
//
// pre1 = dinv[v]*(sum_{e:dst=v} Y[src] + Y[v]) + b1,  Y = (x@W1) row-scaled by dinv (bf16)
// zs   = (relu(pre1).W2) * dinv
// out  = relu(dinv[v]*(sum zs[src] + zs[v]) + b2), sliced v%15 in 3..14
//
// Round-8 lesson kept: no device-scope ticket/fence fusion — kernel boundaries
// are cheaper than cross-XCD fence chains.

#define BK 256        // nodes per bucket
#define NBMAX 640     // >= NB=586
#define EPB 4096      // edges per block for hist/place (293 blocks -> covers all CUs)
#define HB 320        // padded per-bucket row length (>= NBLK=293)

typedef unsigned int uint;
typedef unsigned short ushort;
typedef __attribute__((ext_vector_type(8))) short bf16x8_t;
typedef __attribute__((ext_vector_type(4))) float f32x4_t;

static __device__ __forceinline__ ushort f2bf(float x) {
    uint u = __float_as_uint(x);
    u = (u + 0x7FFFu + ((u >> 16) & 1u)) >> 16;   // RN-even
    return (ushort)u;
}

// per-block LDS histogram of dst>>8 -> hist[j*HB + b]
__global__ __launch_bounds__(256) void k_hist(const int* __restrict__ dst, int E, int nb,
                                              int* __restrict__ hist) {
    __shared__ int h[NBMAX];
    const int t = threadIdx.x, b = blockIdx.x;
    for (int j = t; j < nb; j += 256) h[j] = 0;
    __syncthreads();
    const int e0 = b * EPB, e1 = min(e0 + EPB, E);
    for (int e = e0 + t; e < e1; e += 256) atomicAdd(&h[dst[e] >> 8], 1);
    __syncthreads();
    for (int j = t; j < nb; j += 256) hist[j * HB + b] = h[j];
}

// per bucket j: exclusive prefix over nblk blocks (chunked, in place); total -> colsum[j]
__global__ __launch_bounds__(256) void k_cscan1(int* __restrict__ hist, int nblk,
                                                int* __restrict__ colsum) {
    __shared__ int s[256];
    const int j = blockIdx.x, t = threadIdx.x;
    int carry = 0;
    for (int base = 0; base < nblk; base += 256) {
        int idx = base + t;
        int v = (idx < nblk) ? hist[j * HB + idx] : 0;
        __syncthreads();
        s[t] = v;
        __syncthreads();
        for (int o = 1; o < 256; o <<= 1) {
            int x = s[t];
            if (t >= o) x += s[t - o];
            __syncthreads();
            s[t] = x;
            __syncthreads();
        }
        if (idx < nblk) hist[j * HB + idx] = carry + s[t] - v;
        carry += s[255];
    }
    if (t == 0) colsum[j] = carry;
}

// single block: exclusive scan colsum[nb] -> boff[nb+1]; rowptr[N] = E
__global__ __launch_bounds__(1024) void k_cscan2(const int* __restrict__ colsum, int nb, int N,
                                                 int* __restrict__ boff, int* __restrict__ rowptr) {
    __shared__ int s[1024];
    const int t = threadIdx.x;
    int v = (t < nb) ? colsum[t] : 0;
    s[t] = v;
    __syncthreads();
    for (int o = 1; o < 1024; o <<= 1) {
        int x = s[t];
        if (t >= o) x += s[t - o];
        __syncthreads();
        s[t] = x;
        __syncthreads();
    }
    if (t < nb) boff[t] = s[t] - v;
    if (t == nb - 1) { boff[nb] = s[t]; rowptr[N] = s[t]; }
}

// place edges into per-(block,bucket) reserved chunks (clustered writes, LDS cursors)
__global__ __launch_bounds__(256) void k_place(const int* __restrict__ src, const int* __restrict__ dst,
                                               int E, int nb, const int* __restrict__ hist,
                                               const int* __restrict__ boff, uint* __restrict__ ebuf) {
    __shared__ int cur[NBMAX];
    const int t = threadIdx.x, b = blockIdx.x;
    for (int j = t; j < nb; j += 256) cur[j] = boff[j] + hist[j * HB + b];
    __syncthreads();
    const int e0 = b * EPB, e1 = min(e0 + EPB, E);
    for (int e = e0 + t; e < e1; e += 256) {
        int d = dst[e];
        int p = atomicAdd(&cur[d >> 8], 1);
        ebuf[p] = ((uint)(d & 255) << 24) | (uint)src[e];
    }
}

// per bucket: node histogram (=deg) -> dinv + rowptr (local scan) + csrc placement
__global__ __launch_bounds__(256) void k_fill3(const uint* __restrict__ ebuf, const int* __restrict__ boff,
                                               int N, int* __restrict__ rowptr, float* __restrict__ dinv,
                                               int* __restrict__ csrc) {
    __shared__ int cnt[BK];
    __shared__ int sc[BK];
    __shared__ int cur[BK];
    const int b = blockIdx.x, v0 = b << 8, t = threadIdx.x;
    const int nv = min(BK, N - v0);
    cnt[t] = 0;
    __syncthreads();
    const int bb = boff[b], be = boff[b + 1];
    for (int j = bb + t; j < be; j += 256) atomicAdd(&cnt[ebuf[j] >> 24], 1);
    __syncthreads();
    const int c = cnt[t];
    if (t < nv) dinv[v0 + t] = rsqrtf((float)c + 1.0f);
    sc[t] = c;
    __syncthreads();
    for (int o = 1; o < 256; o <<= 1) {
        int x = sc[t];
        if (t >= o) x += sc[t - o];
        __syncthreads();
        sc[t] = x;
        __syncthreads();
    }
    const int ex = sc[t] - c + bb;
    if (t < nv) rowptr[v0 + t] = ex;
    cur[t] = ex;
    __syncthreads();
    for (int j = bb + t; j < be; j += 256) {
        uint e = ebuf[j];
        int p = atomicAdd(&cur[e >> 24], 1);
        csrc[p] = (int)(e & 0xFFFFFFu);
    }
}

// MFMA feature transform: Y = (X @ W1) * dinv, emitted bf16.
// Block = 256 threads = 4 waves; 2 tiles of 64 rows (W staged once per 128 rows).
// C-tile staged in LDS, then written out as uint4 (8 bf16) fully coalesced.
__global__ __launch_bounds__(256) void k_gemm1(const float* __restrict__ X, const float* __restrict__ W,
                                               const float* __restrict__ dinv, int N,
                                               ushort* __restrict__ Yh) {
    __shared__ __align__(16) ushort Wt[64 * 72];  // Wt[col][k]
    __shared__ __align__(16) ushort Ot[64 * 72];  // C tile (bf16, scaled)
    const int t = threadIdx.x;

    // stage W^T as bf16 (once per block)
#pragma unroll
    for (int i = 0; i < 4; i++) {
        int idx = t + i * 256;          // float4 index, 0..1023
        int k = idx >> 4;
        int c4 = idx & 15;
        float4 w4 = ((const float4*)W)[idx];
        Wt[(c4 * 4 + 0) * 72 + k] = f2bf(w4.x);
        Wt[(c4 * 4 + 1) * 72 + k] = f2bf(w4.y);
        Wt[(c4 * 4 + 2) * 72 + k] = f2bf(w4.z);
        Wt[(c4 * 4 + 3) * 72 + k] = f2bf(w4.w);
    }
    __syncthreads();

    const int l = t & 63;
    const int lr = l & 15;                       // A-row / B-col within tile
    const int g = l >> 4;                        // k-group
    const int wv = t >> 6;                       // wave id

#pragma unroll
    for (int tile = 0; tile < 2; tile++) {
        const int row0 = blockIdx.x * 128 + tile * 64;
        const int rw = row0 + wv * 16;           // wave's row base

        // A fragments for the two K=32 steps (row = rw+lr, k = s*32 + g*8 + i)
        bf16x8_t afr[2];
#pragma unroll
        for (int s = 0; s < 2; s++) {
            const int row = rw + lr;
            float4 xa = make_float4(0.f, 0.f, 0.f, 0.f), xb = xa;
            if (row < N) {
                const float4* xp = (const float4*)(X + (size_t)row * 64 + s * 32 + g * 8);
                xa = xp[0];
                xb = xp[1];
            }
            bf16x8_t af;
            af[0] = (short)f2bf(xa.x); af[1] = (short)f2bf(xa.y);
            af[2] = (short)f2bf(xa.z); af[3] = (short)f2bf(xa.w);
            af[4] = (short)f2bf(xb.x); af[5] = (short)f2bf(xb.y);
            af[6] = (short)f2bf(xb.z); af[7] = (short)f2bf(xb.w);
            afr[s] = af;
        }

        // dinv for this lane's 4 C-rows (reads past N stay inside the workspace)
        const float4 dv = *(const float4*)(dinv + rw + g * 4);

#pragma unroll
        for (int c = 0; c < 4; c++) {
            f32x4_t acc = {0.f, 0.f, 0.f, 0.f};
#pragma unroll
            for (int s = 0; s < 2; s++) {
                const bf16x8_t bf = *(const bf16x8_t*)&Wt[(c * 16 + lr) * 72 + s * 32 + g * 8];
                acc = __builtin_amdgcn_mfma_f32_16x16x32_bf16(afr[s], bf, acc, 0, 0, 0);
            }
            const int col = c * 16 + lr;
#pragma unroll
            for (int r = 0; r < 4; r++) {
                const float sc = (r == 0) ? dv.x : (r == 1) ? dv.y : (r == 2) ? dv.z : dv.w;
                Ot[(wv * 16 + g * 4 + r) * 72 + col] = f2bf(acc[r] * sc);
            }
        }
        __syncthreads();

        // vectorized writeout: 2 x uint4 (8 bf16) per thread, fully coalesced
#pragma unroll
        for (int i = 0; i < 2; i++) {
            int vi = t + i * 256;            // 0..511
            int row = vi >> 3;
            int c8 = vi & 7;
            int grow = row0 + row;
            if (grow < N)
                ((uint4*)(Yh + (size_t)grow * 64))[c8] = *(const uint4*)&Ot[row * 72 + c8 * 8];
        }
        __syncthreads();   // Ot reused by next tile
    }
}

// Fused layer-1 gather + bias/relu + dot(W2) + *dinv -> zs.
// 8 lanes per node; lane li owns features 8li..8li+7 (uint4 = 8 bf16).
// Next chunk's indices prefetched while current chunk's row loads are in flight.
__global__ __launch_bounds__(256) void k_agg(const ushort* __restrict__ Yh, const int* __restrict__ rowptr,
                                             const int* __restrict__ csrc, const float* __restrict__ dinv,
                                             const float* __restrict__ b1, const float* __restrict__ W2,
                                             int N, float* __restrict__ zs) {
    int t = blockIdx.x * 256 + threadIdx.x;
    int v = t >> 3;
    if (v >= N) return;
    int li = t & 7;
    const uint4* Y4 = (const uint4*)Yh;
    int start = rowptr[v];
    int cnt = rowptr[v + 1] - start;

    float a[8];
    {
        uint4 m = Y4[(size_t)v * 8 + li];  // self-loop term
        a[0] = __uint_as_float(m.x << 16);
        a[1] = __uint_as_float(m.x & 0xFFFF0000u);
        a[2] = __uint_as_float(m.y << 16);
        a[3] = __uint_as_float(m.y & 0xFFFF0000u);
        a[4] = __uint_as_float(m.z << 16);
        a[5] = __uint_as_float(m.z & 0xFFFF0000u);
        a[6] = __uint_as_float(m.w << 16);
        a[7] = __uint_as_float(m.w & 0xFFFF0000u);
    }

    int idx = (li < cnt) ? csrc[start + li] : 0;   // first chunk's indices
    for (int j0 = 0; j0 < cnt; j0 += 8) {
        int rem = cnt - j0;
        int nxt = 0;
        if (li < rem - 8) nxt = csrc[start + j0 + 8 + li];  // prefetch next chunk
#pragma unroll
        for (int k = 0; k < 8; k++) {
            if (k < rem) {
                int s = __shfl(idx, k, 8);
                uint4 m = Y4[(size_t)s * 8 + li];     // independent 16B loads -> ILP
                a[0] += __uint_as_float(m.x << 16);
                a[1] += __uint_as_float(m.x & 0xFFFF0000u);
                a[2] += __uint_as_float(m.y << 16);
                a[3] += __uint_as_float(m.y & 0xFFFF0000u);
                a[4] += __uint_as_float(m.z << 16);
                a[5] += __uint_as_float(m.z & 0xFFFF0000u);
                a[6] += __uint_as_float(m.w << 16);
                a[7] += __uint_as_float(m.w & 0xFFFF0000u);
            }
        }
        idx = nxt;
    }

    float dv = dinv[v];
    float4 ba = ((const float4*)b1)[2 * li], bb = ((const float4*)b1)[2 * li + 1];
    float4 wa = ((const float4*)W2)[2 * li], wb = ((const float4*)W2)[2 * li + 1];
    float p;
    p  = fmaxf(fmaf(dv, a[0], ba.x), 0.f) * wa.x;
    p += fmaxf(fmaf(dv, a[1], ba.y), 0.f) * wa.y;
    p += fmaxf(fmaf(dv, a[2], ba.z), 0.f) * wa.z;
    p += fmaxf(fmaf(dv, a[3], ba.w), 0.f) * wa.w;
    p += fmaxf(fmaf(dv, a[4], bb.x), 0.f) * wb.x;
    p += fmaxf(fmaf(dv, a[5], bb.y), 0.f) * wb.y;
    p += fmaxf(fmaf(dv, a[6], bb.z), 0.f) * wb.z;
    p += fmaxf(fmaf(dv, a[7], bb.w), 0.f) * wb.w;
    p += __shfl_xor(p, 1);
    p += __shfl_xor(p, 2);
    p += __shfl_xor(p, 4);
    if (li == 0) zs[v] = p * dv;
}

// layer-2 scalar gather + output slice: v = (i/12)*15 + 3 + i%12
__global__ __launch_bounds__(256) void k_out2(const float* __restrict__ zs, const int* __restrict__ rowptr,
                                              const int* __restrict__ csrc, const float* __restrict__ dinv,
                                              const float* __restrict__ b2, int M, float* __restrict__ out) {
    int i = blockIdx.x * 256 + threadIdx.x;
    if (i >= M) return;
    int q = i / 12;
    int c = i - q * 12;
    int v = q * 15 + 3 + c;
    int j = rowptr[v];
    const int end = rowptr[v + 1];
    float s = zs[v];
    for (; j + 4 <= end; j += 4) {
        int i0 = csrc[j], i1 = csrc[j + 1], i2 = csrc[j + 2], i3 = csrc[j + 3];
        s += zs[i0] + zs[i1] + zs[i2] + zs[i3];   // 4 independent L2-hot loads
    }
    for (; j < end; j++) s += zs[csrc[j]];
    out[i] = fmaxf(fmaf(dinv[v], s, b2[0]), 0.f);
}

extern "C" void kernel_launch(void* const* d_in, const int* in_sizes, int n_in,
                              void* d_out, int out_size, void* d_ws, size_t ws_size,
                              hipStream_t stream) {
    const float* obs = (const float*)d_in[0];
    const int*   ei  = (const int*)d_in[1];   // [2,E]; JAX x64-off -> int32
    const float* W1  = (const float*)d_in[2];
    const float* b1  = (const float*)d_in[3];
    const float* W2  = (const float*)d_in[4];
    const float* b2  = (const float*)d_in[5];

    const int N = in_sizes[0] / 64;
    const int E = in_sizes[1] / 2;
    const int M = out_size;
    const int NB = (N + BK - 1) / BK;          // 586
    const int NBLK = (E + EPB - 1) / EPB;      // 293 (<= HB)

    const int* src = ei;
    const int* dst = ei + E;

    // workspace layout
    ushort* Yh     = (ushort*)d_ws;                  // N*64 bf16 (19.2 MB)
    float*  dinv   = (float*)(Yh + (size_t)N * 64);  // N
    float*  zs     = dinv + N;                       // N
    int*    rowptr = (int*)(zs + N);                 // N+1
    int*    colsum = rowptr + N + 1;                 // NBMAX
    int*    boff   = colsum + NBMAX;                 // NBMAX+1
    int*    hist   = boff + NBMAX + 1;               // NBMAX*HB (800 KB)
    uint*   ebuf   = (uint*)(hist + NBMAX * HB);     // E (4.8 MB)
    int*    csrc   = (int*)(ebuf + E);               // E (4.8 MB)

    k_hist  <<<NBLK, 256, 0, stream>>>(dst, E, NB, hist);
    k_cscan1<<<NB, 256, 0, stream>>>(hist, NBLK, colsum);
    k_cscan2<<<1, 1024, 0, stream>>>(colsum, NB, N, boff, rowptr);
    k_place <<<NBLK, 256, 0, stream>>>(src, dst, E, NB, hist, boff, ebuf);
    k_fill3 <<<NB, 256, 0, stream>>>(ebuf, boff, N, rowptr, dinv, csrc);
    k_gemm1 <<<(N + 127) / 128, 256, 0, stream>>>(obs, W1, dinv, N, Yh);
    k_agg   <<<((size_t)N * 8 + 255) / 256, 256, 0, stream>>>(Yh, rowptr, csrc, dinv, b1, W2, N, zs);
    k_out2  <<<(M + 255) / 256, 256, 0, stream>>>(zs, rowptr, csrc, dinv, b2, M, (float*)d_out);
}

// Round 11
// 89.265 us; speedup vs baseline: 1.5761x; 1.0709x over previous
//
#include <hip/hip_runtime.h>
#include <hip/hip_bf16.h>

// GCN 2-layer forward on MI355X — atomic-free clustered CSR build + pipelined
// 8-lane gather + MFMA bf16 feature transform (packed cvt, LDS epilogue).
// N=150000, E=1.2M, IN=HID=64, layer-2 out dim = 1.
//
// pre1 = dinv[v]*(sum_{e:dst=v} Y[src] + Y[v]) + b1,  Y = (x@W1) row-scaled by dinv (bf16)
// zs   = (relu(pre1).W2) * dinv
// out  = relu(dinv[v]*(sum zs[src] + zs[v]) + b2), sliced v%15 in 3..14
//
// Round-8 lesson kept: no device-scope ticket/fence fusion — kernel boundaries
// are cheaper than cross-XCD fence chains.

#define BK 256        // nodes per bucket
#define NBMAX 640     // >= NB=586
#define EPB 4096      // edges per block for hist/place (293 blocks)
#define HB 320        // padded per-bucket row length (>= NBLK=293)
#define FCAP 3072     // LDS edge-stage capacity in k_fill3 (mean bucket = 2048)

typedef unsigned int uint;
typedef unsigned short ushort;
typedef __attribute__((ext_vector_type(8))) short bf16x8_t;
typedef __attribute__((ext_vector_type(4))) float f32x4_t;

static __device__ __forceinline__ ushort f2bf(float x) {
    uint u = __float_as_uint(x);
    u = (u + 0x7FFFu + ((u >> 16) & 1u)) >> 16;   // RN-even
    return (ushort)u;
}

// packed f32x2 -> bf16x2 (compiler emits v_cvt_pk_bf16_f32)
static __device__ __forceinline__ uint pk2(float a, float b) {
    __hip_bfloat162 h = __float22bfloat162_rn(make_float2(a, b));
    return *(uint*)&h;
}

// per-block LDS histogram of dst>>8 -> hist[j*HB + b]
__global__ __launch_bounds__(256) void k_hist(const int* __restrict__ dst, int E, int nb,
                                              int* __restrict__ hist) {
    __shared__ int h[NBMAX];
    const int t = threadIdx.x, b = blockIdx.x;
    for (int j = t; j < nb; j += 256) h[j] = 0;
    __syncthreads();
    const int e0 = b * EPB, e1 = min(e0 + EPB, E);
    if ((((size_t)dst) & 15) == 0) {
        const int nfull = (e1 - e0) & ~3;
        const int4* d4 = (const int4*)(dst + e0);
        for (int i = t; i < (nfull >> 2); i += 256) {
            int4 d = d4[i];
            atomicAdd(&h[d.x >> 8], 1); atomicAdd(&h[d.y >> 8], 1);
            atomicAdd(&h[d.z >> 8], 1); atomicAdd(&h[d.w >> 8], 1);
        }
        for (int e = e0 + nfull + t; e < e1; e += 256) atomicAdd(&h[dst[e] >> 8], 1);
    } else {
        for (int e = e0 + t; e < e1; e += 256) atomicAdd(&h[dst[e] >> 8], 1);
    }
    __syncthreads();
    for (int j = t; j < nb; j += 256) hist[j * HB + b] = h[j];
}

// per bucket j: exclusive prefix over nblk blocks (chunked, in place); total -> colsum[j]
__global__ __launch_bounds__(256) void k_cscan1(int* __restrict__ hist, int nblk,
                                                int* __restrict__ colsum) {
    __shared__ int s[256];
    const int j = blockIdx.x, t = threadIdx.x;
    int carry = 0;
    for (int base = 0; base < nblk; base += 256) {
        int idx = base + t;
        int v = (idx < nblk) ? hist[j * HB + idx] : 0;
        __syncthreads();
        s[t] = v;
        __syncthreads();
        for (int o = 1; o < 256; o <<= 1) {
            int x = s[t];
            if (t >= o) x += s[t - o];
            __syncthreads();
            s[t] = x;
            __syncthreads();
        }
        if (idx < nblk) hist[j * HB + idx] = carry + s[t] - v;
        carry += s[255];
    }
    if (t == 0) colsum[j] = carry;
}

// single block: exclusive scan colsum[nb] -> boff[nb+1]; rowptr[N] = E
__global__ __launch_bounds__(1024) void k_cscan2(const int* __restrict__ colsum, int nb, int N,
                                                 int* __restrict__ boff, int* __restrict__ rowptr) {
    __shared__ int s[1024];
    const int t = threadIdx.x;
    int v = (t < nb) ? colsum[t] : 0;
    s[t] = v;
    __syncthreads();
    for (int o = 1; o < 1024; o <<= 1) {
        int x = s[t];
        if (t >= o) x += s[t - o];
        __syncthreads();
        s[t] = x;
        __syncthreads();
    }
    if (t < nb) boff[t] = s[t] - v;
    if (t == nb - 1) { boff[nb] = s[t]; rowptr[N] = s[t]; }
}

// place edges into per-(block,bucket) reserved chunks (clustered writes, LDS cursors)
__global__ __launch_bounds__(256) void k_place(const int* __restrict__ src, const int* __restrict__ dst,
                                               int E, int nb, const int* __restrict__ hist,
                                               const int* __restrict__ boff, uint* __restrict__ ebuf) {
    __shared__ int cur[NBMAX];
    const int t = threadIdx.x, b = blockIdx.x;
    for (int j = t; j < nb; j += 256) cur[j] = boff[j] + hist[j * HB + b];
    __syncthreads();
    const int e0 = b * EPB, e1 = min(e0 + EPB, E);
    if (((((size_t)dst) | ((size_t)src)) & 15) == 0) {
        const int nfull = (e1 - e0) & ~3;
        const int4* d4 = (const int4*)(dst + e0);
        const int4* s4 = (const int4*)(src + e0);
        for (int i = t; i < (nfull >> 2); i += 256) {
            int4 d = d4[i];
            int4 s = s4[i];
            int p;
            p = atomicAdd(&cur[d.x >> 8], 1); ebuf[p] = ((uint)(d.x & 255) << 24) | (uint)s.x;
            p = atomicAdd(&cur[d.y >> 8], 1); ebuf[p] = ((uint)(d.y & 255) << 24) | (uint)s.y;
            p = atomicAdd(&cur[d.z >> 8], 1); ebuf[p] = ((uint)(d.z & 255) << 24) | (uint)s.z;
            p = atomicAdd(&cur[d.w >> 8], 1); ebuf[p] = ((uint)(d.w & 255) << 24) | (uint)s.w;
        }
        for (int e = e0 + nfull + t; e < e1; e += 256) {
            int d = dst[e];
            int p = atomicAdd(&cur[d >> 8], 1);
            ebuf[p] = ((uint)(d & 255) << 24) | (uint)src[e];
        }
    } else {
        for (int e = e0 + t; e < e1; e += 256) {
            int d = dst[e];
            int p = atomicAdd(&cur[d >> 8], 1);
            ebuf[p] = ((uint)(d & 255) << 24) | (uint)src[e];
        }
    }
}

// per bucket: node histogram (=deg) -> dinv + rowptr (local scan) + csrc placement.
// Bucket's edges staged in LDS on the first pass (cap FCAP, global fallback).
__global__ __launch_bounds__(256) void k_fill3(const uint* __restrict__ ebuf, const int* __restrict__ boff,
                                               int N, int* __restrict__ rowptr, float* __restrict__ dinv,
                                               int* __restrict__ csrc) {
    __shared__ int cnt[BK];
    __shared__ int sc[BK];
    __shared__ int cur[BK];
    __shared__ uint se[FCAP];
    const int b = blockIdx.x, v0 = b << 8, t = threadIdx.x;
    const int nv = min(BK, N - v0);
    cnt[t] = 0;
    __syncthreads();
    const int bb = boff[b], be = boff[b + 1];
    const int ne = be - bb;
    for (int j = t; j < ne; j += 256) {
        uint e = ebuf[bb + j];
        if (j < FCAP) se[j] = e;
        atomicAdd(&cnt[e >> 24], 1);
    }
    __syncthreads();
    const int c = cnt[t];
    if (t < nv) dinv[v0 + t] = rsqrtf((float)c + 1.0f);
    sc[t] = c;
    __syncthreads();
    for (int o = 1; o < 256; o <<= 1) {
        int x = sc[t];
        if (t >= o) x += sc[t - o];
        __syncthreads();
        sc[t] = x;
        __syncthreads();
    }
    const int ex = sc[t] - c + bb;
    if (t < nv) rowptr[v0 + t] = ex;
    cur[t] = ex;
    __syncthreads();
    for (int j = t; j < ne; j += 256) {
        uint e = (j < FCAP) ? se[j] : ebuf[bb + j];
        int p = atomicAdd(&cur[e >> 24], 1);
        csrc[p] = (int)(e & 0xFFFFFFu);
    }
}

// MFMA feature transform: Y = (X @ W1) * dinv, emitted bf16.
// Block = 256 threads = 4 waves; 2 tiles of 64 rows (W staged once per 128 rows).
// Packed v_cvt_pk_bf16_f32 converts; C-tile staged in LDS, uint4 coalesced writeout.
__global__ __launch_bounds__(256) void k_gemm1(const float* __restrict__ X, const float* __restrict__ W,
                                               const float* __restrict__ dinv, int N,
                                               ushort* __restrict__ Yh) {
    __shared__ __align__(16) ushort Wt[64 * 72];  // Wt[col][k]
    __shared__ __align__(16) ushort Ot[64 * 72];  // C tile (bf16, scaled)
    const int t = threadIdx.x;

    // stage W^T as bf16 (once per block)
#pragma unroll
    for (int i = 0; i < 4; i++) {
        int idx = t + i * 256;          // float4 index, 0..1023
        int k = idx >> 4;
        int c4 = idx & 15;
        float4 w4 = ((const float4*)W)[idx];
        Wt[(c4 * 4 + 0) * 72 + k] = f2bf(w4.x);
        Wt[(c4 * 4 + 1) * 72 + k] = f2bf(w4.y);
        Wt[(c4 * 4 + 2) * 72 + k] = f2bf(w4.z);
        Wt[(c4 * 4 + 3) * 72 + k] = f2bf(w4.w);
    }
    __syncthreads();

    const int l = t & 63;
    const int lr = l & 15;                       // A-row / B-col within tile
    const int g = l >> 4;                        // k-group
    const int wv = t >> 6;                       // wave id

#pragma unroll
    for (int tile = 0; tile < 2; tile++) {
        const int row0 = blockIdx.x * 128 + tile * 64;
        const int rw = row0 + wv * 16;           // wave's row base

        // A fragments for the two K=32 steps (row = rw+lr, k = s*32 + g*8 + i)
        bf16x8_t afr[2];
#pragma unroll
        for (int s = 0; s < 2; s++) {
            const int row = rw + lr;
            float4 xa = make_float4(0.f, 0.f, 0.f, 0.f), xb = xa;
            if (row < N) {
                const float4* xp = (const float4*)(X + (size_t)row * 64 + s * 32 + g * 8);
                xa = xp[0];
                xb = xp[1];
            }
            uint4 ua;
            ua.x = pk2(xa.x, xa.y);
            ua.y = pk2(xa.z, xa.w);
            ua.z = pk2(xb.x, xb.y);
            ua.w = pk2(xb.z, xb.w);
            afr[s] = __builtin_bit_cast(bf16x8_t, ua);
        }

        // dinv for this lane's 4 C-rows (reads past N stay inside the workspace)
        const float4 dv = *(const float4*)(dinv + rw + g * 4);

#pragma unroll
        for (int c = 0; c < 4; c++) {
            f32x4_t acc = {0.f, 0.f, 0.f, 0.f};
#pragma unroll
            for (int s = 0; s < 2; s++) {
                const bf16x8_t bf = *(const bf16x8_t*)&Wt[(c * 16 + lr) * 72 + s * 32 + g * 8];
                acc = __builtin_amdgcn_mfma_f32_16x16x32_bf16(afr[s], bf, acc, 0, 0, 0);
            }
            const int col = c * 16 + lr;
            const int rb = wv * 16 + g * 4;
            uint u01 = pk2(acc[0] * dv.x, acc[1] * dv.y);
            uint u23 = pk2(acc[2] * dv.z, acc[3] * dv.w);
            Ot[(rb + 0) * 72 + col] = (ushort)(u01 & 0xFFFFu);
            Ot[(rb + 1) * 72 + col] = (ushort)(u01 >> 16);
            Ot[(rb + 2) * 72 + col] = (ushort)(u23 & 0xFFFFu);
            Ot[(rb + 3) * 72 + col] = (ushort)(u23 >> 16);
        }
        __syncthreads();

        // vectorized writeout: 2 x uint4 (8 bf16) per thread, fully coalesced
#pragma unroll
        for (int i = 0; i < 2; i++) {
            int vi = t + i * 256;            // 0..511
            int row = vi >> 3;
            int c8 = vi & 7;
            int grow = row0 + row;
            if (grow < N)
                ((uint4*)(Yh + (size_t)grow * 64))[c8] = *(const uint4*)&Ot[row * 72 + c8 * 8];
        }
        __syncthreads();   // Ot reused by next tile
    }
}

// Fused layer-1 gather + bias/relu + dot(W2) + *dinv -> zs.
// 8 lanes per node; lane li owns features 8li..8li+7 (uint4 = 8 bf16).
// Next chunk's indices prefetched while current chunk's row loads are in flight.
__global__ __launch_bounds__(256) void k_agg(const ushort* __restrict__ Yh, const int* __restrict__ rowptr,
                                             const int* __restrict__ csrc, const float* __restrict__ dinv,
                                             const float* __restrict__ b1, const float* __restrict__ W2,
                                             int N, float* __restrict__ zs) {
    int t = blockIdx.x * 256 + threadIdx.x;
    int v = t >> 3;
    if (v >= N) return;
    int li = t & 7;
    const uint4* Y4 = (const uint4*)Yh;
    int start = rowptr[v];
    int cnt = rowptr[v + 1] - start;

    float a[8];
    {
        uint4 m = Y4[(size_t)v * 8 + li];  // self-loop term
        a[0] = __uint_as_float(m.x << 16);
        a[1] = __uint_as_float(m.x & 0xFFFF0000u);
        a[2] = __uint_as_float(m.y << 16);
        a[3] = __uint_as_float(m.y & 0xFFFF0000u);
        a[4] = __uint_as_float(m.z << 16);
        a[5] = __uint_as_float(m.z & 0xFFFF0000u);
        a[6] = __uint_as_float(m.w << 16);
        a[7] = __uint_as_float(m.w & 0xFFFF0000u);
    }

    int idx = (li < cnt) ? csrc[start + li] : 0;   // first chunk's indices
    for (int j0 = 0; j0 < cnt; j0 += 8) {
        int rem = cnt - j0;
        int nxt = 0;
        if (li < rem - 8) nxt = csrc[start + j0 + 8 + li];  // prefetch next chunk
#pragma unroll
        for (int k = 0; k < 8; k++) {
            if (k < rem) {
                int s = __shfl(idx, k, 8);
                uint4 m = Y4[(size_t)s * 8 + li];     // independent 16B loads -> ILP
                a[0] += __uint_as_float(m.x << 16);
                a[1] += __uint_as_float(m.x & 0xFFFF0000u);
                a[2] += __uint_as_float(m.y << 16);
                a[3] += __uint_as_float(m.y & 0xFFFF0000u);
                a[4] += __uint_as_float(m.z << 16);
                a[5] += __uint_as_float(m.z & 0xFFFF0000u);
                a[6] += __uint_as_float(m.w << 16);
                a[7] += __uint_as_float(m.w & 0xFFFF0000u);
            }
        }
        idx = nxt;
    }

    float dv = dinv[v];
    float4 ba = ((const float4*)b1)[2 * li], bb = ((const float4*)b1)[2 * li + 1];
    float4 wa = ((const float4*)W2)[2 * li], wb = ((const float4*)W2)[2 * li + 1];
    float p;
    p  = fmaxf(fmaf(dv, a[0], ba.x), 0.f) * wa.x;
    p += fmaxf(fmaf(dv, a[1], ba.y), 0.f) * wa.y;
    p += fmaxf(fmaf(dv, a[2], ba.z), 0.f) * wa.z;
    p += fmaxf(fmaf(dv, a[3], ba.w), 0.f) * wa.w;
    p += fmaxf(fmaf(dv, a[4], bb.x), 0.f) * wb.x;
    p += fmaxf(fmaf(dv, a[5], bb.y), 0.f) * wb.y;
    p += fmaxf(fmaf(dv, a[6], bb.z), 0.f) * wb.z;
    p += fmaxf(fmaf(dv, a[7], bb.w), 0.f) * wb.w;
    p += __shfl_xor(p, 1);
    p += __shfl_xor(p, 2);
    p += __shfl_xor(p, 4);
    if (li == 0) zs[v] = p * dv;
}

// layer-2 scalar gather + output slice: v = (i/12)*15 + 3 + i%12
__global__ __launch_bounds__(256) void k_out2(const float* __restrict__ zs, const int* __restrict__ rowptr,
                                              const int* __restrict__ csrc, const float* __restrict__ dinv,
                                              const float* __restrict__ b2, int M, float* __restrict__ out) {
    int i = blockIdx.x * 256 + threadIdx.x;
    if (i >= M) return;
    int q = i / 12;
    int c = i - q * 12;
    int v = q * 15 + 3 + c;
    int j = rowptr[v];
    const int end = rowptr[v + 1];
    float s = zs[v];
    for (; j + 4 <= end; j += 4) {
        int i0 = csrc[j], i1 = csrc[j + 1], i2 = csrc[j + 2], i3 = csrc[j + 3];
        s += zs[i0] + zs[i1] + zs[i2] + zs[i3];   // 4 independent L2-hot loads
    }
    for (; j < end; j++) s += zs[csrc[j]];
    out[i] = fmaxf(fmaf(dinv[v], s, b2[0]), 0.f);
}

extern "C" void kernel_launch(void* const* d_in, const int* in_sizes, int n_in,
                              void* d_out, int out_size, void* d_ws, size_t ws_size,
                              hipStream_t stream) {
    const float* obs = (const float*)d_in[0];
    const int*   ei  = (const int*)d_in[1];   // [2,E]; JAX x64-off -> int32
    const float* W1  = (const float*)d_in[2];
    const float* b1  = (const float*)d_in[3];
    const float* W2  = (const float*)d_in[4];
    const float* b2  = (const float*)d_in[5];

    const int N = in_sizes[0] / 64;
    const int E = in_sizes[1] / 2;
    const int M = out_size;
    const int NB = (N + BK - 1) / BK;          // 586
    const int NBLK = (E + EPB - 1) / EPB;      // 293 (<= HB)

    const int* src = ei;
    const int* dst = ei + E;

    // workspace layout
    ushort* Yh     = (ushort*)d_ws;                  // N*64 bf16 (19.2 MB)
    float*  dinv   = (float*)(Yh + (size_t)N * 64);  // N
    float*  zs     = dinv + N;                       // N
    int*    rowptr = (int*)(zs + N);                 // N+1
    int*    colsum = rowptr + N + 1;                 // NBMAX
    int*    boff   = colsum + NBMAX;                 // NBMAX+1
    int*    hist   = boff + NBMAX + 1;               // NBMAX*HB (800 KB)
    uint*   ebuf   = (uint*)(hist + NBMAX * HB);     // E (4.8 MB)
    int*    csrc   = (int*)(ebuf + E);               // E (4.8 MB)

    k_hist  <<<NBLK, 256, 0, stream>>>(dst, E, NB, hist);
    k_cscan1<<<NB, 256, 0, stream>>>(hist, NBLK, colsum);
    k_cscan2<<<1, 1024, 0, stream>>>(colsum, NB, N, boff, rowptr);
    k_place <<<NBLK, 256, 0, stream>>>(src, dst, E, NB, hist, boff, ebuf);
    k_fill3 <<<NB, 256, 0, stream>>>(ebuf, boff, N, rowptr, dinv, csrc);
    k_gemm1 <<<(N + 127) / 128, 256, 0, stream>>>(obs, W1, dinv, N, Yh);
    k_agg   <<<((size_t)N * 8 + 255) / 256, 256, 0, stream>>>(Yh, rowptr, csrc, dinv, b1, W2, N, zs);
    k_out2  <<<(M + 255) / 256, 256, 0, stream>>>(zs, rowptr, csrc, dinv, b2, M, (float*)d_out);
}